// Round 1
// 181.758 us; speedup vs baseline: 1.2515x; 1.2515x over previous
//
#include <hip/hip_runtime.h>

#define NB   32
#define NT   784
#define NC   768
#define NH   4
#define CH   192
#define PSZ  14
#define NP   196
#define RESO 28
#define EPSV 1e-5f

// ---------------------------------------------------------------------------
// K1: separable position softmax. s(i,j) = w0*dx + w1*dy + w2*(dx^2+dy^2) + pb
// factorizes as exp(ax)*exp(by)*exp(pb); softmax over i = Fn(jx,ix)*Gn(jy,iy)
// with per-axis normalization (pb cancels). One block of 64 threads:
// thread t<56 handles (h = t/14, j = t%14) for both axes. Also sigmoid gates.
// ---------------------------------------------------------------------------
__global__ __launch_bounds__(64) void k_pos(
    const float* __restrict__ pos_w, const float* __restrict__ pos_b,
    const float* __restrict__ mnw,   const float* __restrict__ vnw,
    float* __restrict__ fn, float* __restrict__ gn, float* __restrict__ mwvw) {
  int t = threadIdx.x;
  if (t < 8) {
    float v = (t < 4) ? mnw[t] : vnw[t - 4];
    mwvw[t] = 1.f / (1.f + expf(-v));
  }
  if (t < NH * PSZ) {
    int h = t / PSZ, j = t % PSZ;
    float w0 = pos_w[h * 3 + 0];
    float w1 = pos_w[h * 3 + 1];
    float w2 = pos_w[h * 3 + 2];
    float e[PSZ];

    // F: x-axis factor, a(ix) = w0*(j-ix) + w2*(j-ix)^2
    float mx = -1e30f;
#pragma unroll
    for (int i = 0; i < PSZ; ++i) {
      float d = (float)(j - i);
      float s = w0 * d + w2 * d * d;
      e[i] = s;
      mx = fmaxf(mx, s);
    }
    float sum = 0.f;
#pragma unroll
    for (int i = 0; i < PSZ; ++i) { e[i] = expf(e[i] - mx); sum += e[i]; }
    float inv = 1.f / sum;
#pragma unroll
    for (int i = 0; i < PSZ; ++i) fn[(h * PSZ + j) * PSZ + i] = e[i] * inv;

    // G: y-axis factor, b(iy) = w1*(j-iy) + w2*(j-iy)^2
    mx = -1e30f;
#pragma unroll
    for (int i = 0; i < PSZ; ++i) {
      float d = (float)(j - i);
      float s = w1 * d + w2 * d * d;
      e[i] = s;
      mx = fmaxf(mx, s);
    }
    sum = 0.f;
#pragma unroll
    for (int i = 0; i < PSZ; ++i) { e[i] = expf(e[i] - mx); sum += e[i]; }
    inv = 1.f / sum;
#pragma unroll
    for (int i = 0; i < PSZ; ++i) gn[(h * PSZ + j) * PSZ + i] = e[i] * inv;
  }
}

// ---------------------------------------------------------------------------
// K2: wave-per-token group-m2 norm + per-token mean/var + 2x2 pool.
// grid = NB*NP blocks of 256 (4 waves = 4 tokens of one patch). UNCHANGED.
// ---------------------------------------------------------------------------
__global__ __launch_bounds__(256) void k_norm_pool(
    const float* __restrict__ x,
    float* __restrict__ inv_m2, float* __restrict__ mean_ln,
    float* __restrict__ var_ln, float4* __restrict__ xp4) {
  __shared__ float4 xl4[4 * 192];  // 12.3 KB
  int bid = blockIdx.x;
  int b = bid / NP, ip = bid % NP;
  int pr = ip / PSZ, pc = ip % PSZ;
  int tid = threadIdx.x;
  int k = tid >> 6, lane = tid & 63;
  int t = (2 * pr + (k >> 1)) * RESO + (2 * pc + (k & 1));

  const float4* row = (const float4*)(x + (size_t)(b * NT + t) * NC);
  float4 v0 = row[lane], v1 = row[lane + 64], v2 = row[lane + 128];
  int h0 = lane / 48;            // 0 or 1
  int h1 = (lane + 64) / 48;     // 1 or 2
  int h2 = (lane + 128) / 48;    // 2 or 3

  float d0 = v0.x * v0.x + v0.y * v0.y + v0.z * v0.z + v0.w * v0.w;
  float d1 = v1.x * v1.x + v1.y * v1.y + v1.z * v1.z + v1.w * v1.w;
  float d2 = v2.x * v2.x + v2.y * v2.y + v2.z * v2.z + v2.w * v2.w;
  float s0 = (h0 == 0) ? d0 : 0.f;
  float s1 = ((h0 == 1) ? d0 : 0.f) + ((h1 == 1) ? d1 : 0.f);
  float s2 = ((h1 == 2) ? d1 : 0.f) + ((h2 == 2) ? d2 : 0.f);
  float s3 = (h2 == 3) ? d2 : 0.f;
#pragma unroll
  for (int d = 32; d >= 1; d >>= 1) {
    s0 += __shfl_xor(s0, d, 64);
    s1 += __shfl_xor(s1, d, 64);
    s2 += __shfl_xor(s2, d, 64);
    s3 += __shfl_xor(s3, d, 64);
  }
  float i0 = rsqrtf(s0 * (1.f / CH) + EPSV);
  float i1 = rsqrtf(s1 * (1.f / CH) + EPSV);
  float i2 = rsqrtf(s2 * (1.f / CH) + EPSV);
  float i3 = rsqrtf(s3 * (1.f / CH) + EPSV);
  if (lane < 4) {
    float iv = (lane == 0) ? i0 : (lane == 1) ? i1 : (lane == 2) ? i2 : i3;
    inv_m2[(size_t)(b * NT + t) * NH + lane] = iv;
  }

  float f0 = (h0 == 0) ? i0 : i1;
  float f1 = (h1 == 1) ? i1 : i2;
  float f2 = (h2 == 2) ? i2 : i3;
  v0.x *= f0; v0.y *= f0; v0.z *= f0; v0.w *= f0;
  v1.x *= f1; v1.y *= f1; v1.z *= f1; v1.w *= f1;
  v2.x *= f2; v2.y *= f2; v2.z *= f2; v2.w *= f2;

  float sm = v0.x + v0.y + v0.z + v0.w + v1.x + v1.y + v1.z + v1.w +
             v2.x + v2.y + v2.z + v2.w;
  float sq = v0.x * v0.x + v0.y * v0.y + v0.z * v0.z + v0.w * v0.w +
             v1.x * v1.x + v1.y * v1.y + v1.z * v1.z + v1.w * v1.w +
             v2.x * v2.x + v2.y * v2.y + v2.z * v2.z + v2.w * v2.w;
#pragma unroll
  for (int d = 32; d >= 1; d >>= 1) {
    sm += __shfl_xor(sm, d, 64);
    sq += __shfl_xor(sq, d, 64);
  }
  if (lane == 0) {
    float mean = sm / (float)NC;
    mean_ln[b * NT + t] = mean;
    var_ln[b * NT + t] = (sq - (float)NC * mean * mean) / (float)(NC - 1);
  }

  xl4[k * 192 + lane] = v0;
  xl4[k * 192 + lane + 64] = v1;
  xl4[k * 192 + lane + 128] = v2;
  __syncthreads();

  if (tid < 192) {
    float4 a = xl4[tid], bb = xl4[192 + tid], c = xl4[384 + tid], d = xl4[576 + tid];
    float4 r;
    r.x = (a.x + bb.x + c.x + d.x) * 0.25f;
    r.y = (a.y + bb.y + c.y + d.y) * 0.25f;
    r.z = (a.z + bb.z + c.z + d.z) * 0.25f;
    r.w = (a.w + bb.w + c.w + d.w) * 0.25f;
    xp4[(size_t)(b * NP + ip) * 192 + tid] = r;
  }
}

// ---------------------------------------------------------------------------
// K3: separable conv + blend + affine + store. grid = NB*PSZ blocks of 256;
// bid = b*14 + jx (one patch-COLUMN per block = 14 patches = 56 tokens).
// Wave h owns channels h*192 + lane + 64*{0,1,2}.
// Pass A: t1[iy] = sum_ix Fn[jx,ix]*xp[iy*14+ix], t2 same with xp^2 (registers).
// Pass B per jy: mean_r = sum_iy Gn[jy,iy]*t1[iy] (registers) -> epilogue.
// ---------------------------------------------------------------------------
__global__ __launch_bounds__(256) void k_fused(
    const float* __restrict__ xp, const float* __restrict__ fn,
    const float* __restrict__ gn, const float* __restrict__ x,
    const float* __restrict__ weight, const float* __restrict__ bias,
    const float* __restrict__ inv_m2, const float* __restrict__ mean_ln,
    const float* __restrict__ var_ln, const float* __restrict__ mwvw,
    float* __restrict__ out) {
  __shared__ float fns[NH * PSZ];        // F row for this jx, per head
  __shared__ float gns[NH * PSZ * PSZ];  // full G tables
  __shared__ float tstat[4 * PSZ][6];    // per local token: inv_m2[4], mean, var

  int bid = blockIdx.x;
  int b = bid / PSZ, jx = bid % PSZ;
  int tid = threadIdx.x;
  int h = tid >> 6, lane = tid & 63;
  int c0 = h * CH + lane, c1 = c0 + 64, c2 = c0 + 128;

  if (tid < NH * PSZ) {
    int hh = tid / PSZ, ix = tid % PSZ;
    fns[tid] = fn[(hh * PSZ + jx) * PSZ + ix];
  }
  for (int i = tid; i < NH * PSZ * PSZ; i += 256) gns[i] = gn[i];
  for (int idx = tid; idx < 4 * PSZ * 6; idx += 256) {
    int l = idx / 6, f = idx % 6;
    int jy = l >> 2, kk = l & 3;
    int t = (2 * jy + (kk >> 1)) * RESO + (2 * jx + (kk & 1));
    size_t o = (size_t)(b * NT + t);
    tstat[l][f] = (f < 4) ? inv_m2[o * NH + f]
                : (f == 4) ? mean_ln[o] : var_ln[o];
  }
  __syncthreads();

  // ---- Pass A: x-direction 14-tap contraction, accumulators in registers
  float t1[PSZ][3], t2[PSZ][3];
#pragma unroll
  for (int iy = 0; iy < PSZ; ++iy)
#pragma unroll
    for (int k = 0; k < 3; ++k) { t1[iy][k] = 0.f; t2[iy][k] = 0.f; }

  const float* base = xp + (size_t)b * NP * NC;
#pragma unroll
  for (int iy = 0; iy < PSZ; ++iy) {
    const float* prow = base + (size_t)iy * PSZ * NC;
#pragma unroll
    for (int ix = 0; ix < PSZ; ++ix) {
      float f = fns[h * PSZ + ix];  // wave-uniform LDS broadcast
      const float* row = prow + ix * NC;
      float v0 = row[c0], v1 = row[c1], v2 = row[c2];
      t1[iy][0] += f * v0; t2[iy][0] += f * (v0 * v0);
      t1[iy][1] += f * v1; t2[iy][1] += f * (v1 * v1);
      t1[iy][2] += f * v2; t2[iy][2] += f * (v2 * v2);
    }
  }

  // ---- Pass B + epilogue
  float wv0 = weight[c0], wv1 = weight[c1], wv2 = weight[c2];
  float bv0 = bias[c0],   bv1 = bias[c1],   bv2 = bias[c2];
  float mw = mwvw[h], vw = mwvw[4 + h];
  float omw = 1.f - mw, ovw = 1.f - vw;
  const float* gh = &gns[h * NP];

#pragma unroll 1   // keep jy as a real loop (I$); t1/t2 indices stay static below
  for (int jy = 0; jy < PSZ; ++jy) {
    float m0 = 0.f, m1 = 0.f, m2v = 0.f, q0 = 0.f, q1 = 0.f, q2 = 0.f;
#pragma unroll
    for (int iy = 0; iy < PSZ; ++iy) {
      float g = gh[jy * PSZ + iy];  // wave-uniform LDS broadcast
      m0  += g * t1[iy][0]; q0 += g * t2[iy][0];
      m1  += g * t1[iy][1]; q1 += g * t2[iy][1];
      m2v += g * t1[iy][2]; q2 += g * t2[iy][2];
    }
    float p0 = fmaxf(q0 - m0 * m0, 0.f);
    float p1 = fmaxf(q1 - m1 * m1, 0.f);
    float p2 = fmaxf(q2 - m2v * m2v, 0.f);
    float mb0 = omw * m0, mb1 = omw * m1, mb2 = omw * m2v;
    float vb0 = ovw * p0, vb1 = ovw * p1, vb2 = ovw * p2;

#pragma unroll
    for (int kk = 0; kk < 4; ++kk) {
      int t = (2 * jy + (kk >> 1)) * RESO + (2 * jx + (kk & 1));
      size_t xo = (size_t)(b * NT + t) * NC;
      int l = jy * 4 + kk;
      float iv = tstat[l][h];
      float ml = tstat[l][4], vl = tstat[l][5];

      float xn0 = x[xo + c0] * iv;
      float xn1 = x[xo + c1] * iv;
      float xn2 = x[xo + c2] * iv;

      float mr0 = mb0 + mw * ml;
      float mr1 = mb1 + mw * ml;
      float mr2 = mb2 + mw * ml;
      float vr0 = vb0 + vw * vl;
      float vr1 = vb1 + vw * vl;
      float vr2 = vb2 + vw * vl;

      out[xo + c0] = (xn0 - mr0) * rsqrtf(vr0 + EPSV) * wv0 + bv0;
      out[xo + c1] = (xn1 - mr1) * rsqrtf(vr1 + EPSV) * wv1 + bv1;
      out[xo + c2] = (xn2 - mr2) * rsqrtf(vr2 + EPSV) * wv2 + bv2;
    }
  }
}

// ---------------------------------------------------------------------------
extern "C" void kernel_launch(void* const* d_in, const int* in_sizes, int n_in,
                              void* d_out, int out_size, void* d_ws, size_t ws_size,
                              hipStream_t stream) {
  const float* x     = (const float*)d_in[0];
  const float* wgt   = (const float*)d_in[1];
  const float* bias  = (const float*)d_in[2];
  const float* mnw   = (const float*)d_in[3];
  const float* vnw   = (const float*)d_in[4];
  const float* pos_w = (const float*)d_in[5];
  const float* pos_b = (const float*)d_in[6];
  float* out = (float*)d_out;

  float* ws      = (float*)d_ws;
  float* fn      = ws;                              // NH*14*14 = 784
  float* gn      = fn + NH * PSZ * PSZ;             // 784
  float* mwvw    = gn + NH * PSZ * PSZ;             // 8
  float* inv_m2  = mwvw + 8;                        // NB*NT*NH = 100352
  float* mean_ln = inv_m2 + (size_t)NB * NT * NH;   // 25088
  float* var_ln  = mean_ln + (size_t)NB * NT;       // 25088
  float* xp      = var_ln + (size_t)NB * NT;        // NB*NP*NC = 4816896 (16B aligned)
  // total ~19.9 MB of workspace (less than previous version's ~20.5 MB)

  hipLaunchKernelGGL(k_pos, dim3(1), dim3(64), 0, stream,
                     pos_w, pos_b, mnw, vnw, fn, gn, mwvw);
  hipLaunchKernelGGL(k_norm_pool, dim3(NB * NP), dim3(256), 0, stream,
                     x, inv_m2, mean_ln, var_ln, (float4*)xp);
  hipLaunchKernelGGL(k_fused, dim3(NB * PSZ), dim3(256), 0, stream,
                     xp, fn, gn, x, wgt, bias, inv_m2, mean_ln, var_ln, mwvw, out);
}

// Round 3
// 177.255 us; speedup vs baseline: 1.2833x; 1.0254x over previous
//
#include <hip/hip_runtime.h>

#define NB   32
#define NT   784
#define NC   768
#define NH   4
#define CH   192
#define PSZ  14
#define NP   196
#define RESO 28
#define EPSV 1e-5f

// ---------------------------------------------------------------------------
// K1: wave-per-token group-m2 norm + per-token mean/var + 2x2 pool.
// grid = NB*NP blocks of 256 (4 waves = 4 tokens of one patch).
// Head-aligned lanes: lane L owns head L/16, channels (L%16)*12..+11
// -> m2 reduce is 4 shfl rounds within a 16-lane group (no masking).
// ---------------------------------------------------------------------------
__global__ __launch_bounds__(256) void k_norm_pool(
    const float* __restrict__ x,
    float* __restrict__ inv_m2, float* __restrict__ mean_ln,
    float* __restrict__ var_ln, float4* __restrict__ xp4) {
  __shared__ float4 xl4[4 * 192];  // 12.3 KB
  int bid = blockIdx.x;
  int b = bid / NP, ip = bid % NP;
  int pr = ip / PSZ, pc = ip % PSZ;
  int tid = threadIdx.x;
  int k = tid >> 6, lane = tid & 63;
  int t = (2 * pr + (k >> 1)) * RESO + (2 * pc + (k & 1));

  const float4* row = (const float4*)(x + (size_t)(b * NT + t) * NC);
  int f4b = (lane >> 4) * 48 + (lane & 15) * 3;  // lane's base float4 index
  float4 v0 = row[f4b], v1 = row[f4b + 1], v2 = row[f4b + 2];

  // group-m2: all 12 channels of this lane belong to one head
  float d = v0.x * v0.x + v0.y * v0.y + v0.z * v0.z + v0.w * v0.w +
            v1.x * v1.x + v1.y * v1.y + v1.z * v1.z + v1.w * v1.w +
            v2.x * v2.x + v2.y * v2.y + v2.z * v2.z + v2.w * v2.w;
#pragma unroll
  for (int s = 1; s <= 8; s <<= 1) d += __shfl_xor(d, s, 64);
  float iv = rsqrtf(d * (1.f / CH) + EPSV);
  if ((lane & 15) == 0)
    inv_m2[(size_t)(b * NT + t) * NH + (lane >> 4)] = iv;

  v0.x *= iv; v0.y *= iv; v0.z *= iv; v0.w *= iv;
  v1.x *= iv; v1.y *= iv; v1.z *= iv; v1.w *= iv;
  v2.x *= iv; v2.y *= iv; v2.z *= iv; v2.w *= iv;

  float sm = v0.x + v0.y + v0.z + v0.w + v1.x + v1.y + v1.z + v1.w +
             v2.x + v2.y + v2.z + v2.w;
  float sq = v0.x * v0.x + v0.y * v0.y + v0.z * v0.z + v0.w * v0.w +
             v1.x * v1.x + v1.y * v1.y + v1.z * v1.z + v1.w * v1.w +
             v2.x * v2.x + v2.y * v2.y + v2.z * v2.z + v2.w * v2.w;
#pragma unroll
  for (int s = 1; s <= 32; s <<= 1) {
    sm += __shfl_xor(sm, s, 64);
    sq += __shfl_xor(sq, s, 64);
  }
  if (lane == 0) {
    float mean = sm / (float)NC;
    mean_ln[b * NT + t] = mean;
    var_ln[b * NT + t] = (sq - (float)NC * mean * mean) / (float)(NC - 1);
  }

  xl4[k * 192 + f4b]     = v0;
  xl4[k * 192 + f4b + 1] = v1;
  xl4[k * 192 + f4b + 2] = v2;
  __syncthreads();

  if (tid < 192) {
    float4 a = xl4[tid], bb = xl4[192 + tid], c = xl4[384 + tid], dd = xl4[576 + tid];
    float4 r;
    r.x = (a.x + bb.x + c.x + dd.x) * 0.25f;
    r.y = (a.y + bb.y + c.y + dd.y) * 0.25f;
    r.z = (a.z + bb.z + c.z + dd.z) * 0.25f;
    r.w = (a.w + bb.w + c.w + dd.w) * 0.25f;
    xp4[(size_t)(b * NP + ip) * 192 + tid] = r;
  }
}

// ---------------------------------------------------------------------------
// K2: separable conv + blend + affine + store, with in-block pos tables.
// grid = NB*3*PSZ blocks of 256 (XCD-swizzled); block = (b, channel-slice s,
// patch-column jx). Thread owns ONE channel c = h*192 + s*64 + lane.
// Pass A: t1[iy] = sum_ix Fn[jx,ix]*xp, t2 same with xp^2 (registers).
// Pass B per jy: contract with Gn over iy -> epilogue for 4 tokens.
// ---------------------------------------------------------------------------
__global__ __launch_bounds__(256) void k_fused(
    const float* __restrict__ xp, const float* __restrict__ pos_w,
    const float* __restrict__ mnw, const float* __restrict__ vnw,
    const float* __restrict__ x,
    const float* __restrict__ weight, const float* __restrict__ bias,
    const float* __restrict__ inv_m2, const float* __restrict__ mean_ln,
    const float* __restrict__ var_ln, float* __restrict__ out) {
  __shared__ float fns[NH * PSZ];        // F row for this jx, per head
  __shared__ float gns[NH * PSZ * PSZ];  // full G tables
  __shared__ float tstat[4 * PSZ][6];    // per local token: inv_m2[4], mean, var
  __shared__ float sgate[8];             // sigmoid(mnw), sigmoid(vnw)

  int bid0 = blockIdx.x;
  int bid = (bid0 & 7) * 168 + (bid0 >> 3);  // bijective XCD swizzle (1344=8*168)
  int b = bid / 42, r = bid % 42;
  int s = r / PSZ, jx = r % PSZ;
  int tid = threadIdx.x;
  int h = tid >> 6, lane = tid & 63;
  int c = h * CH + s * 64 + lane;

  // ---- in-block separable softmax tables (disjoint thread ranges!)
  if (tid < NH * PSZ) {                  // tid 0..55: G row, head tid/14, jy=tid%14
    int hh = tid / PSZ, jr = tid % PSZ;
    float w1 = pos_w[hh * 3 + 1], w2 = pos_w[hh * 3 + 2];
    float e[PSZ], mx = -1e30f;
#pragma unroll
    for (int i = 0; i < PSZ; ++i) {
      float dd = (float)(jr - i);
      float sc = w1 * dd + w2 * dd * dd;
      e[i] = sc; mx = fmaxf(mx, sc);
    }
    float sum = 0.f;
#pragma unroll
    for (int i = 0; i < PSZ; ++i) { e[i] = expf(e[i] - mx); sum += e[i]; }
    float invs = 1.f / sum;
#pragma unroll
    for (int i = 0; i < PSZ; ++i) gns[(hh * PSZ + jr) * PSZ + i] = e[i] * invs;
  }
  if (tid >= 64 && tid < 64 + NH) {      // tid 64..67: F row for this jx, head tid-64
    int hh = tid - 64;
    float w0 = pos_w[hh * 3 + 0], w2 = pos_w[hh * 3 + 2];
    float e[PSZ], mx = -1e30f;
#pragma unroll
    for (int i = 0; i < PSZ; ++i) {
      float dd = (float)(jx - i);
      float sc = w0 * dd + w2 * dd * dd;
      e[i] = sc; mx = fmaxf(mx, sc);
    }
    float sum = 0.f;
#pragma unroll
    for (int i = 0; i < PSZ; ++i) { e[i] = expf(e[i] - mx); sum += e[i]; }
    float invs = 1.f / sum;
#pragma unroll
    for (int i = 0; i < PSZ; ++i) fns[hh * PSZ + i] = e[i] * invs;
  }
  if (tid >= 72 && tid < 80) {           // tid 72..79: sigmoid gates
    int g = tid - 72;
    float v = (g < 4) ? mnw[g] : vnw[g - 4];
    sgate[g] = 1.f / (1.f + expf(-v));
  }
  for (int idx = tid; idx < 4 * PSZ * 6; idx += 256) {
    int l = idx / 6, f = idx % 6;
    int jy = l >> 2, kk = l & 3;
    int t = (2 * jy + (kk >> 1)) * RESO + (2 * jx + (kk & 1));
    size_t o = (size_t)(b * NT + t);
    tstat[l][f] = (f < 4) ? inv_m2[o * NH + f]
                : (f == 4) ? mean_ln[o] : var_ln[o];
  }
  __syncthreads();

  // ---- Pass A: x-direction 14-tap contraction, accumulators in registers
  float t1[PSZ], t2[PSZ];
#pragma unroll
  for (int iy = 0; iy < PSZ; ++iy) { t1[iy] = 0.f; t2[iy] = 0.f; }

  const float* base = xp + (size_t)b * NP * NC + c;
#pragma unroll
  for (int iy = 0; iy < PSZ; ++iy) {
    const float* prow = base + (size_t)(iy * PSZ) * NC;
#pragma unroll
    for (int ix = 0; ix < PSZ; ++ix) {
      float f = fns[h * PSZ + ix];  // wave-uniform LDS broadcast
      float v = prow[ix * NC];
      t1[iy] += f * v;
      t2[iy] += f * (v * v);
    }
  }

  // ---- Pass B + epilogue
  float wv = weight[c], bv = bias[c];
  float mw = sgate[h], vw = sgate[4 + h];
  float omw = 1.f - mw, ovw = 1.f - vw;
  const float* gh = &gns[h * NP];

#pragma unroll 1
  for (int jy = 0; jy < PSZ; ++jy) {
    float m = 0.f, q = 0.f;
#pragma unroll
    for (int iy = 0; iy < PSZ; ++iy) {
      float g = gh[jy * PSZ + iy];  // wave-uniform LDS broadcast
      m += g * t1[iy];
      q += g * t2[iy];
    }
    float p = fmaxf(q - m * m, 0.f);
    float mb = omw * m, vb = ovw * p;

#pragma unroll
    for (int kk = 0; kk < 4; ++kk) {
      int t = (2 * jy + (kk >> 1)) * RESO + (2 * jx + (kk & 1));
      size_t xo = (size_t)(b * NT + t) * NC;
      int l = jy * 4 + kk;
      float ivv = tstat[l][h];
      float ml = tstat[l][4], vl = tstat[l][5];

      float xn = x[xo + c] * ivv;
      float mr = mb + mw * ml;
      float vr = vb + vw * vl;
      out[xo + c] = (xn - mr) * rsqrtf(vr + EPSV) * wv + bv;
    }
  }
}

// ---------------------------------------------------------------------------
extern "C" void kernel_launch(void* const* d_in, const int* in_sizes, int n_in,
                              void* d_out, int out_size, void* d_ws, size_t ws_size,
                              hipStream_t stream) {
  const float* x     = (const float*)d_in[0];
  const float* wgt   = (const float*)d_in[1];
  const float* bias  = (const float*)d_in[2];
  const float* mnw   = (const float*)d_in[3];
  const float* vnw   = (const float*)d_in[4];
  const float* pos_w = (const float*)d_in[5];
  // pos_b (d_in[6]) cancels in the softmax — unused.
  float* out = (float*)d_out;

  float* ws      = (float*)d_ws;
  float* inv_m2  = ws;                              // NB*NT*NH = 100352
  float* mean_ln = inv_m2 + (size_t)NB * NT * NH;   // 25088
  float* var_ln  = mean_ln + (size_t)NB * NT;       // 25088
  float* xp      = var_ln + (size_t)NB * NT;        // NB*NP*NC = 4816896 (16B aligned)
  // total ~19.9 MB of workspace

  hipLaunchKernelGGL(k_norm_pool, dim3(NB * NP), dim3(256), 0, stream,
                     x, inv_m2, mean_ln, var_ln, (float4*)xp);
  hipLaunchKernelGGL(k_fused, dim3(NB * 3 * PSZ), dim3(256), 0, stream,
                     xp, pos_w, mnw, vnw, x, wgt, bias, inv_m2, mean_ln, var_ln, out);
}